// Round 16
// baseline (457.370 us; speedup 1.0000x reference)
//
#include <hip/hip_runtime.h>

// Acoustic stress-velocity FD propagator, MI355X — persistent kernel v16.
// v15's fused one-barrier step + PROVEN all-far (sc0 sc1) protocol,
// re-gridded to 512 blocks x 768 threads = 2 blocks/CU so one block's
// compute hides the other's sync chain. Rationale: v15 measured C=7.1us >
// S=4.6us per epoch; period P = max(2*C_half, C_half + S) < C + S now
// (v7's null result was the C<S regime where overlap can't help).
// Tiles 16x32 (grid 16x8 per shot), region 48x64, TS=16, NEP=25.
// Shadow recomputation, parity double-buffer, flag transitivity, proxy
// polls: bit-identical to v15.

#define NXc 256
#define NZc 256
#define NTc 400
#define NSc 4
#define NRc 128

#define TS 16                   // steps per epoch = halo depth
#define BTX 16                  // tile x-extent
#define BTZ 32                  // tile z-extent
#define ROWS (BTX + 2*TS)       // 48 region rows (x)
#define LROW (BTZ + 2*TS)       // 64 region cols (z)
#define NSTR (LROW/4)           // 16 strips per row
#define BT (ROWS * NSTR)        // 768 threads
#define SPSZ ((ROWS + 2) * LROW) // 3200 per p-buffer (pad row each side)
#define NTX 16                  // tile grid x (per shot)
#define NTZ 8                   // tile grid z (per shot)
#define NBLK (NSc * NTX * NTZ)  // 512 blocks
#define NEP (NTc / TS)          // 25 epochs

constexpr float DT_H    = 0.001f;
constexpr float INV_D   = 0.1f;            // 1/DX = 1/DZ
constexpr float SRC_AMP = 0.001f * 0.01f;  // DT/(DX*DZ)
constexpr int   NXZ     = NXc * NZc;

typedef float f32x4 __attribute__((ext_vector_type(4)));

__device__ __forceinline__ unsigned ldu_far(const unsigned* p) {
    unsigned v;
    asm volatile("global_load_dword %0, %1, off sc0 sc1\n\t"
                 "s_waitcnt vmcnt(0)" : "=&v"(v) : "v"(p) : "memory");
    return v;
}
__device__ __forceinline__ void stu_far(unsigned* p, unsigned v) {
    asm volatile("global_store_dword %0, %1, off sc0 sc1"
                 :: "v"(p), "v"(v) : "memory");
}

__global__ __launch_bounds__(BT) void prop_kernel(
    float* __restrict__ xchg, unsigned* __restrict__ flags,
    const float* __restrict__ vp, const float* __restrict__ rho,
    const float* __restrict__ damp, const float* __restrict__ wavelet,
    const int* __restrict__ src_x, const int* __restrict__ src_z,
    const int* __restrict__ rcv_x, const int* __restrict__ rcv_z,
    float* __restrict__ out)
{
    __shared__ float sp[2 * SPSZ];   // double-buffered p (A=0, B=SPSZ)

    const int tid  = threadIdx.x;
    const int bid  = blockIdx.x;
    const int s    = bid >> 7;            // 128 tiles per shot
    const int tile = bid & 127;
    const int tx = tile >> 3, tz = tile & 7;
    const int gx0 = tx * BTX - TS, gz0 = tz * BTZ - TS;

    const int li  = tid >> 4;              // region row 0..47
    const int st  = tid & 15;              // strip 0..15
    const int lk0 = st * 4;
    const int gi  = gx0 + li;
    const int gk0 = gz0 + lk0;             // 4-aligned; strip fully in or out
    const bool in = ((unsigned)gi < (unsigned)NXc) &&
                    ((unsigned)gk0 < (unsigned)NZc);
    const int c4 = s * NXZ + gi * NZc + gk0;
    const bool central = in && ((unsigned)(li - TS) < (unsigned)BTX)
                            && (lk0 >= TS) && (lk0 <= TS + BTZ - 4);
    const bool ring = in && !central;

    const size_t F = (size_t)NSc * NXZ;
    float* b0 = xchg;            // epoch parity 0: {p, vx, vz}
    float* b1 = xchg + 3 * F;    // epoch parity 1

    // ---- state + time-invariant coefficients (registers, once) ----
    float pr[4]  = {0, 0, 0, 0};
    float vxr[4] = {0, 0, 0, 0};
    float vzr[4] = {0, 0, 0, 0};
    float vxm[4] = {0, 0, 0, 0};   // shadow: vx of row R-1
    float vzm    = 0.f;            // shadow: vz of cell (gi, gk0-1)
    float fr[4], bxr[4], bzr[4], dkxr[4], dkzr[4], sfr[4];
    float fxm[4], bxm[4];          // row R-1 coefficients
    float fzm = 0.f, bzm = 0.f;    // cell (gi, gk0-1) coefficients
    {
        const int sx = src_x[s], sz = src_z[s];
        if (in) {
            const int g = gi * NZc + gk0;
            float4 r4 = *(const float4*)(rho  + g);
            float4 v4 = *(const float4*)(vp   + g);
            float4 d4 = *(const float4*)(damp + g);
            float rv[4] = {r4.x, r4.y, r4.z, r4.w};
            float vv[4] = {v4.x, v4.y, v4.z, v4.w};
            float dv[4] = {d4.x, d4.y, d4.z, d4.w};
#pragma unroll
            for (int k = 0; k < 4; ++k) {
                int gk = gk0 + k;
                fr[k] = 1.0f - DT_H * dv[k];
                float bi = DT_H / rv[k] * INV_D;
                bxr[k] = (gi == NXc - 1) ? 0.f : bi;   // _dxf zero-pad
                bzr[k] = (gk == NZc - 1) ? 0.f : bi;   // _dzf zero-pad
                float dk = DT_H * rv[k] * vv[k] * vv[k] * INV_D;
                dkxr[k] = (gi == 0) ? 0.f : dk;        // _dxb zero-pad
                dkzr[k] = (gk == 0) ? 0.f : dk;        // _dzb zero-pad
                sfr[k]  = (gi == sx && gk == sz) ? SRC_AMP : 0.f;
            }
            if (gi > 0) {
                float4 rm = *(const float4*)(rho  + g - NZc);
                float4 dm = *(const float4*)(damp + g - NZc);
                float rmv[4] = {rm.x, rm.y, rm.z, rm.w};
                float dmv[4] = {dm.x, dm.y, dm.z, dm.w};
#pragma unroll
                for (int k = 0; k < 4; ++k) {
                    fxm[k] = 1.0f - DT_H * dmv[k];
                    bxm[k] = DT_H / rmv[k] * INV_D;
                }
            } else {
#pragma unroll
                for (int k = 0; k < 4; ++k) { fxm[k] = 0.f; bxm[k] = 0.f; }
            }
            if (gk0 > 0) {
                fzm = 1.0f - DT_H * damp[g - 1];
                bzm = DT_H / rho[g - 1] * INV_D;
            }
        } else {
#pragma unroll
            for (int k = 0; k < 4; ++k) {
                fr[k]=0.f; bxr[k]=0.f; bzr[k]=0.f;
                dkxr[k]=0.f; dkzr[k]=0.f; sfr[k]=0.f;
                fxm[k]=0.f; bxm[k]=0.f;
            }
        }
    }

    const int jp = (li + 1) * LROW + lk0;

    // Zero pad rows of BOTH buffers (steps write rows 0..ROWS-1 only).
    if (tid < LROW) {
        sp[tid] = 0.f;               sp[SPSZ - LROW + tid] = 0.f;
        sp[SPSZ + tid] = 0.f;        sp[2 * SPSZ - LROW + tid] = 0.f;
    }

    // Receivers (loaded once).
    int rxv = 0, rzv = 0;
    if (tid < NRc) { rxv = rcv_x[tid]; rzv = rcv_z[tid]; }
    const bool rown = (tid < NRc) &&
        ((unsigned)(rxv - tx * BTX) < (unsigned)BTX) &&
        ((unsigned)(rzv - tz * BTZ) < (unsigned)BTZ);
    const int rj = (rxv - gx0 + 1) * LROW + (rzv - gz0);
    float* obase = out + (size_t)s * NTc * NRc + tid;
    const float* wb = wavelet + s * NTc;

    // Proxy-poll neighbor (tids 0..8, minus center 4).
    int nbid = -1;
    if (tid < 9 && tid != 4) {
        int dx = tid / 3 - 1, dz = tid - (tid / 3) * 3 - 1;
        int nx2 = tx + dx, nz2 = tz + dz;
        if (((unsigned)nx2 < (unsigned)NTX) &&
            ((unsigned)nz2 < (unsigned)NTZ))
            nbid = (s << 7) + nx2 * NTZ + nz2;
    }

    // One fused step: read old p from rdo buffer, write new p to wro.
    auto STEP = [&](int rdo, int wro, int t, bool pub, float* pb) {
        f32x4 pn = *(const f32x4*)&sp[rdo + jp + LROW];   // old p(R+1)
        f32x4 pm = *(const f32x4*)&sp[rdo + jp - LROW];   // old p(R-1)
        float pze = __shfl_down(pr[0], 1, 64);  // next strip p[0] (old)
        float pmz = __shfl_up(pr[3], 1, 64);    // prev strip p[3] (old)
        float pz1[4] = {pr[1], pr[2], pr[3], pze};
#pragma unroll
        for (int k = 0; k < 4; ++k) {
            vxr[k] = fr[k] * vxr[k] - bxr[k] * (pn[k]  - pr[k]);
            vzr[k] = fr[k] * vzr[k] - bzr[k] * (pz1[k] - pr[k]);
        }
#pragma unroll
        for (int k = 0; k < 4; ++k)
            vxm[k] = fxm[k] * vxm[k] - bxm[k] * (pr[k] - pm[k]);
        vzm = fzm * vzm - bzm * (pr[0] - pmz);
        const float wv = wb[t];
        pr[0] = fr[0]*pr[0] - dkxr[0]*(vxr[0]-vxm[0])
              - dkzr[0]*(vzr[0]-vzm) + sfr[0]*wv;
#pragma unroll
        for (int k = 1; k < 4; ++k)
            pr[k] = fr[k]*pr[k] - dkxr[k]*(vxr[k]-vxm[k])
                  - dkzr[k]*(vzr[k]-vzr[k-1]) + sfr[k]*wv;
        if (pub) {
            f32x4 a = {pr[0], pr[1], pr[2], pr[3]};
            f32x4 b = {vxr[0], vxr[1], vxr[2], vxr[3]};
            f32x4 c = {vzr[0], vzr[1], vzr[2], vzr[3]};
            asm volatile(
                "global_store_dwordx4 %0, %3, off sc0 sc1\n\t"
                "global_store_dwordx4 %1, %4, off sc0 sc1\n\t"
                "global_store_dwordx4 %2, %5, off sc0 sc1"
                :: "v"(pb + c4), "v"(pb + F + c4), "v"(pb + 2 * F + c4),
                   "v"(a), "v"(b), "v"(c)
                : "memory");
        }
        *(f32x4*)&sp[wro + jp] = f32x4{pr[0], pr[1], pr[2], pr[3]};
        __syncthreads();
    };

    for (int l = 0; l < NEP; ++l) {
        const bool notLast = (l < NEP - 1);
        float* pb = (l & 1) ? b1 : b0;

        // ---- epoch setup: p -> A; stage vx in B for shadow init ----
        *(f32x4*)&sp[jp]        = f32x4{pr[0], pr[1], pr[2], pr[3]};
        *(f32x4*)&sp[SPSZ + jp] = f32x4{vxr[0], vxr[1], vxr[2], vxr[3]};
        __syncthreads();
        {
            f32x4 vm = *(const f32x4*)&sp[SPSZ + jp - LROW];
            vxm[0]=vm[0]; vxm[1]=vm[1]; vxm[2]=vm[2]; vxm[3]=vm[3];
            vzm = __shfl_up(vzr[3], 1, 64);
        }
        __syncthreads();   // shadow reads done before step 0 writes to B

        // ---- TS fused steps; parity: even rd=A wr=B, odd rd=B wr=A ----
        const int tb = l * TS;
        for (int t2 = 0; t2 < TS; t2 += 2) {
            STEP(0, SPSZ, tb + t2, false, pb);
            if (rown)
                obase[(size_t)(tb + t2) * NRc] = sp[SPSZ + rj];
            const bool lastT = (t2 + 2 == TS);
            STEP(SPSZ, 0, tb + t2 + 1,
                 lastT && notLast && central, pb);
            if (!lastT && rown)
                obase[(size_t)(tb + t2 + 1) * NRc] = sp[rj];
        }

        if (notLast) {
            // Release: drain publish stores, then flag.
            asm volatile("s_waitcnt vmcnt(0)" ::: "memory");
            __syncthreads();
            if (tid == 0) stu_far(flags + bid, (unsigned)(l + 1));
            // last-tau receiver record overlaps the polls (final p in A).
            if (rown) obase[(size_t)(tb + TS - 1) * NRc] = sp[rj];
            // Proxy poll: 8 threads watch the 8 neighbors.
            if (nbid >= 0) {
                const unsigned want = (unsigned)(l + 1);
                const unsigned* fp = flags + nbid;
                while (ldu_far(fp) < want) __builtin_amdgcn_s_sleep(2);
            }
            __syncthreads();
            // Ring reload -> regs (epoch setup re-stages LDS + shadows).
            if (ring) {
                f32x4 a, b, c;
                asm volatile(
                    "global_load_dwordx4 %0, %3, off sc0 sc1\n\t"
                    "global_load_dwordx4 %1, %4, off sc0 sc1\n\t"
                    "global_load_dwordx4 %2, %5, off sc0 sc1\n\t"
                    "s_waitcnt vmcnt(0)"
                    : "=&v"(a), "=&v"(b), "=&v"(c)
                    : "v"(pb + c4), "v"(pb + F + c4), "v"(pb + 2 * F + c4)
                    : "memory");
                pr[0]=a.x; pr[1]=a.y; pr[2]=a.z; pr[3]=a.w;
                vxr[0]=b.x; vxr[1]=b.y; vxr[2]=b.z; vxr[3]=b.w;
                vzr[0]=c.x; vzr[1]=c.y; vzr[2]=c.z; vzr[3]=c.w;
            }
        } else {
            if (rown) obase[(size_t)(tb + TS - 1) * NRc] = sp[rj];
        }
    }
}

extern "C" void kernel_launch(void* const* d_in, const int* in_sizes, int n_in,
                              void* d_out, int out_size, void* d_ws, size_t ws_size,
                              hipStream_t stream)
{
    const float* vp      = (const float*)d_in[0];
    const float* rho     = (const float*)d_in[1];
    const float* damp    = (const float*)d_in[2];
    const float* wavelet = (const float*)d_in[3];
    const int*   src_x   = (const int*)d_in[4];
    const int*   src_z   = (const int*)d_in[5];
    const int*   rcv_x   = (const int*)d_in[6];
    const int*   rcv_z   = (const int*)d_in[7];
    float* out = (float*)d_out;
    float* ws  = (float*)d_ws;

    const size_t F = (size_t)NSc * NXZ;
    float* xchg = ws;                              // 6 fields (2 parities)
    unsigned* flags = (unsigned*)(ws + 6 * F);     // 512 epoch counters

    // Flags must start at 0 every call (ws poisoned once, not re-poisoned).
    hipMemsetAsync(flags, 0, NBLK * sizeof(unsigned), stream);

    prop_kernel<<<NBLK, BT, 0, stream>>>(
        xchg, flags, vp, rho, damp, wavelet,
        src_x, src_z, rcv_x, rcv_z, out);
}

// Round 17
// 300.014 us; speedup vs baseline: 1.5245x; 1.5245x over previous
//
#include <hip/hip_runtime.h>

// Acoustic stress-velocity FD propagator, MI355X — persistent kernel v17.
// v15 (best: 286us) + trapezoid-cone guard: at step tau only rows/cols in
// C(tau)=[tau+1, 63-tau) are computed (~56% of cells on average). Cone
// analysis guarantees every LDS/shuffle read of an active thread targets a
// value written at the previous step (margin exactly 1, double-buffered p).
// Shuffles are hoisted OUTSIDE the guard (ds_bpermute from exec-masked
// lanes is undefined; boundary threads read just-deactivated neighbors'
// registers, which still hold their last-written values). Central threads
// are active at all tau, so publish + receivers are unaffected. Inactive
// threads still hit every barrier. Sync protocol (all-far sc0 sc1, parity
// double-buffer, flag transitivity, proxy polls) bit-identical to v15.
// v16 lesson: co-resident blocks are phase-locked -> 1 block/CU.

#define NXc 256
#define NZc 256
#define NTc 400
#define NSc 4
#define NRc 128

#define TS 16                   // steps per epoch = halo depth
#define Bt 32                   // tile edge
#define LROW 64                 // region edge (z)
#define ROWS 64                 // region edge (x)
#define BT 1024                 // threads = 64 rows x 16 strips
#define SPSZ ((ROWS + 2) * LROW) // 4224 per p-buffer (pad row each side)
#define NBLK (NSc * 64)         // 256 blocks
#define NEP (NTc / TS)          // 25 epochs

constexpr float DT_H    = 0.001f;
constexpr float INV_D   = 0.1f;            // 1/DX = 1/DZ
constexpr float SRC_AMP = 0.001f * 0.01f;  // DT/(DX*DZ)
constexpr int   NXZ     = NXc * NZc;

typedef float f32x4 __attribute__((ext_vector_type(4)));

__device__ __forceinline__ unsigned ldu_far(const unsigned* p) {
    unsigned v;
    asm volatile("global_load_dword %0, %1, off sc0 sc1\n\t"
                 "s_waitcnt vmcnt(0)" : "=&v"(v) : "v"(p) : "memory");
    return v;
}
__device__ __forceinline__ void stu_far(unsigned* p, unsigned v) {
    asm volatile("global_store_dword %0, %1, off sc0 sc1"
                 :: "v"(p), "v"(v) : "memory");
}

__global__ __launch_bounds__(BT) void prop_kernel(
    float* __restrict__ xchg, unsigned* __restrict__ flags,
    const float* __restrict__ vp, const float* __restrict__ rho,
    const float* __restrict__ damp, const float* __restrict__ wavelet,
    const int* __restrict__ src_x, const int* __restrict__ src_z,
    const int* __restrict__ rcv_x, const int* __restrict__ rcv_z,
    float* __restrict__ out)
{
    __shared__ float sp[2 * SPSZ];   // double-buffered p (A=0, B=SPSZ)

    const int tid  = threadIdx.x;
    const int bid  = blockIdx.x;
    const int s    = bid >> 6;
    const int tile = bid & 63;
    const int tx = tile >> 3, tz = tile & 7;
    const int gx0 = tx * Bt - TS, gz0 = tz * Bt - TS;

    const int li  = tid >> 4;              // region row 0..63
    const int st  = tid & 15;              // strip 0..15
    const int lk0 = st * 4;
    const int gi  = gx0 + li;
    const int gk0 = gz0 + lk0;             // 4-aligned; strip fully in or out
    const bool in = ((unsigned)gi < (unsigned)NXc) &&
                    ((unsigned)gk0 < (unsigned)NZc);
    const int c4 = s * NXZ + gi * NZc + gk0;
    const bool central = in && ((unsigned)(li - TS) < (unsigned)Bt)
                            && (lk0 >= TS) && (lk0 <= TS + Bt - 4);
    const bool ring = in && !central;

    const size_t F = (size_t)NSc * NXZ;
    float* b0 = xchg;            // epoch parity 0: {p, vx, vz}
    float* b1 = xchg + 3 * F;    // epoch parity 1

    // ---- state + time-invariant coefficients (registers, once) ----
    float pr[4]  = {0, 0, 0, 0};
    float vxr[4] = {0, 0, 0, 0};
    float vzr[4] = {0, 0, 0, 0};
    float vxm[4] = {0, 0, 0, 0};   // shadow: vx of row R-1
    float vzm    = 0.f;            // shadow: vz of cell (gi, gk0-1)
    float fr[4], bxr[4], bzr[4], dkxr[4], dkzr[4], sfr[4];
    float fxm[4], bxm[4];          // row R-1 coefficients
    float fzm = 0.f, bzm = 0.f;    // cell (gi, gk0-1) coefficients
    {
        const int sx = src_x[s], sz = src_z[s];
        if (in) {
            const int g = gi * NZc + gk0;
            float4 r4 = *(const float4*)(rho  + g);
            float4 v4 = *(const float4*)(vp   + g);
            float4 d4 = *(const float4*)(damp + g);
            float rv[4] = {r4.x, r4.y, r4.z, r4.w};
            float vv[4] = {v4.x, v4.y, v4.z, v4.w};
            float dv[4] = {d4.x, d4.y, d4.z, d4.w};
#pragma unroll
            for (int k = 0; k < 4; ++k) {
                int gk = gk0 + k;
                fr[k] = 1.0f - DT_H * dv[k];
                float bi = DT_H / rv[k] * INV_D;
                bxr[k] = (gi == NXc - 1) ? 0.f : bi;   // _dxf zero-pad
                bzr[k] = (gk == NZc - 1) ? 0.f : bi;   // _dzf zero-pad
                float dk = DT_H * rv[k] * vv[k] * vv[k] * INV_D;
                dkxr[k] = (gi == 0) ? 0.f : dk;        // _dxb zero-pad
                dkzr[k] = (gk == 0) ? 0.f : dk;        // _dzb zero-pad
                sfr[k]  = (gi == sx && gk == sz) ? SRC_AMP : 0.f;
            }
            if (gi > 0) {
                float4 rm = *(const float4*)(rho  + g - NZc);
                float4 dm = *(const float4*)(damp + g - NZc);
                float rmv[4] = {rm.x, rm.y, rm.z, rm.w};
                float dmv[4] = {dm.x, dm.y, dm.z, dm.w};
#pragma unroll
                for (int k = 0; k < 4; ++k) {
                    fxm[k] = 1.0f - DT_H * dmv[k];
                    bxm[k] = DT_H / rmv[k] * INV_D;
                }
            } else {
#pragma unroll
                for (int k = 0; k < 4; ++k) { fxm[k] = 0.f; bxm[k] = 0.f; }
            }
            if (gk0 > 0) {
                fzm = 1.0f - DT_H * damp[g - 1];
                bzm = DT_H / rho[g - 1] * INV_D;
            }
        } else {
#pragma unroll
            for (int k = 0; k < 4; ++k) {
                fr[k]=0.f; bxr[k]=0.f; bzr[k]=0.f;
                dkxr[k]=0.f; dkzr[k]=0.f; sfr[k]=0.f;
                fxm[k]=0.f; bxm[k]=0.f;
            }
        }
    }

    const int jp = (li + 1) * LROW + lk0;

    // Zero pad rows of BOTH buffers (steps write rows 0..63 only).
    if (tid < LROW) {
        sp[tid] = 0.f;               sp[SPSZ - LROW + tid] = 0.f;
        sp[SPSZ + tid] = 0.f;        sp[2 * SPSZ - LROW + tid] = 0.f;
    }

    // Receivers (loaded once).
    int rxv = 0, rzv = 0;
    if (tid < NRc) { rxv = rcv_x[tid]; rzv = rcv_z[tid]; }
    const bool rown = (tid < NRc) &&
        ((unsigned)(rxv - tx * Bt) < (unsigned)Bt) &&
        ((unsigned)(rzv - tz * Bt) < (unsigned)Bt);
    const int rj = (rxv - gx0 + 1) * LROW + (rzv - gz0);
    float* obase = out + (size_t)s * NTc * NRc + tid;
    const float* wb = wavelet + s * NTc;

    // Proxy-poll neighbor (tids 0..8, minus center 4).
    int nbid = -1;
    if (tid < 9 && tid != 4) {
        int dx = tid / 3 - 1, dz = tid - (tid / 3) * 3 - 1;
        int nx2 = tx + dx, nz2 = tz + dz;
        if (((unsigned)nx2 < 8u) && ((unsigned)nz2 < 8u))
            nbid = (s << 6) + nx2 * 8 + nz2;
    }

    // One fused step with trapezoid-cone guard.
    auto STEP = [&](int rdo, int wro, int tau, int t, bool pub, float* pb) {
        // Shuffles first, ALL lanes (masked-lane bpermute is undefined;
        // boundary threads read just-deactivated neighbors' registers).
        float pze = __shfl_down(pr[0], 1, 64);  // next strip p[0] (old)
        float pmz = __shfl_up(pr[3], 1, 64);    // prev strip p[3] (old)
        // Cone guard: C(tau) = [tau+1, 63-tau) in both axes (strip: any
        // of its 4 cells inside).
        const bool act = (li > tau) && (li < 63 - tau) &&
                         (lk0 + 3 > tau) && (lk0 < 63 - tau);
        if (act) {
            f32x4 pn = *(const f32x4*)&sp[rdo + jp + LROW];   // old p(R+1)
            f32x4 pm = *(const f32x4*)&sp[rdo + jp - LROW];   // old p(R-1)
            float pz1[4] = {pr[1], pr[2], pr[3], pze};
#pragma unroll
            for (int k = 0; k < 4; ++k) {
                vxr[k] = fr[k] * vxr[k] - bxr[k] * (pn[k]  - pr[k]);
                vzr[k] = fr[k] * vzr[k] - bzr[k] * (pz1[k] - pr[k]);
            }
#pragma unroll
            for (int k = 0; k < 4; ++k)
                vxm[k] = fxm[k] * vxm[k] - bxm[k] * (pr[k] - pm[k]);
            vzm = fzm * vzm - bzm * (pr[0] - pmz);
            const float wv = wb[t];
            pr[0] = fr[0]*pr[0] - dkxr[0]*(vxr[0]-vxm[0])
                  - dkzr[0]*(vzr[0]-vzm) + sfr[0]*wv;
#pragma unroll
            for (int k = 1; k < 4; ++k)
                pr[k] = fr[k]*pr[k] - dkxr[k]*(vxr[k]-vxm[k])
                      - dkzr[k]*(vzr[k]-vzr[k-1]) + sfr[k]*wv;
            if (pub) {
                f32x4 a = {pr[0], pr[1], pr[2], pr[3]};
                f32x4 b = {vxr[0], vxr[1], vxr[2], vxr[3]};
                f32x4 c = {vzr[0], vzr[1], vzr[2], vzr[3]};
                asm volatile(
                    "global_store_dwordx4 %0, %3, off sc0 sc1\n\t"
                    "global_store_dwordx4 %1, %4, off sc0 sc1\n\t"
                    "global_store_dwordx4 %2, %5, off sc0 sc1"
                    :: "v"(pb + c4), "v"(pb + F + c4),
                       "v"(pb + 2 * F + c4), "v"(a), "v"(b), "v"(c)
                    : "memory");
            }
            *(f32x4*)&sp[wro + jp] = f32x4{pr[0], pr[1], pr[2], pr[3]};
        }
        __syncthreads();
    };

    for (int l = 0; l < NEP; ++l) {
        const bool notLast = (l < NEP - 1);
        float* pb = (l & 1) ? b1 : b0;

        // ---- epoch setup: p -> A; stage vx in B for shadow init ----
        *(f32x4*)&sp[jp]        = f32x4{pr[0], pr[1], pr[2], pr[3]};
        *(f32x4*)&sp[SPSZ + jp] = f32x4{vxr[0], vxr[1], vxr[2], vxr[3]};
        __syncthreads();
        {
            f32x4 vm = *(const f32x4*)&sp[SPSZ + jp - LROW];
            vxm[0]=vm[0]; vxm[1]=vm[1]; vxm[2]=vm[2]; vxm[3]=vm[3];
            vzm = __shfl_up(vzr[3], 1, 64);
        }
        __syncthreads();   // shadow reads done before step 0 writes to B

        // ---- TS fused steps; parity: even rd=A wr=B, odd rd=B wr=A ----
        const int tb = l * TS;
        for (int t2 = 0; t2 < TS; t2 += 2) {
            STEP(0, SPSZ, t2, tb + t2, false, pb);
            if (rown)
                obase[(size_t)(tb + t2) * NRc] = sp[SPSZ + rj];
            const bool lastT = (t2 + 2 == TS);
            STEP(SPSZ, 0, t2 + 1, tb + t2 + 1,
                 lastT && notLast && central, pb);
            if (!lastT && rown)
                obase[(size_t)(tb + t2 + 1) * NRc] = sp[rj];
        }

        if (notLast) {
            // Release: drain publish stores, then flag.
            asm volatile("s_waitcnt vmcnt(0)" ::: "memory");
            __syncthreads();
            if (tid == 0) stu_far(flags + bid, (unsigned)(l + 1));
            // last-tau receiver record overlaps the polls (final p in A).
            if (rown) obase[(size_t)(tb + TS - 1) * NRc] = sp[rj];
            // Proxy poll: 8 threads watch the 8 neighbors.
            if (nbid >= 0) {
                const unsigned want = (unsigned)(l + 1);
                const unsigned* fp = flags + nbid;
                while (ldu_far(fp) < want) __builtin_amdgcn_s_sleep(2);
            }
            __syncthreads();
            // Ring reload -> regs (epoch setup re-stages LDS + shadows).
            if (ring) {
                f32x4 a, b, c;
                asm volatile(
                    "global_load_dwordx4 %0, %3, off sc0 sc1\n\t"
                    "global_load_dwordx4 %1, %4, off sc0 sc1\n\t"
                    "global_load_dwordx4 %2, %5, off sc0 sc1\n\t"
                    "s_waitcnt vmcnt(0)"
                    : "=&v"(a), "=&v"(b), "=&v"(c)
                    : "v"(pb + c4), "v"(pb + F + c4), "v"(pb + 2 * F + c4)
                    : "memory");
                pr[0]=a.x; pr[1]=a.y; pr[2]=a.z; pr[3]=a.w;
                vxr[0]=b.x; vxr[1]=b.y; vxr[2]=b.z; vxr[3]=b.w;
                vzr[0]=c.x; vzr[1]=c.y; vzr[2]=c.z; vzr[3]=c.w;
            }
        } else {
            if (rown) obase[(size_t)(tb + TS - 1) * NRc] = sp[rj];
        }
    }
}

extern "C" void kernel_launch(void* const* d_in, const int* in_sizes, int n_in,
                              void* d_out, int out_size, void* d_ws, size_t ws_size,
                              hipStream_t stream)
{
    const float* vp      = (const float*)d_in[0];
    const float* rho     = (const float*)d_in[1];
    const float* damp    = (const float*)d_in[2];
    const float* wavelet = (const float*)d_in[3];
    const int*   src_x   = (const int*)d_in[4];
    const int*   src_z   = (const int*)d_in[5];
    const int*   rcv_x   = (const int*)d_in[6];
    const int*   rcv_z   = (const int*)d_in[7];
    float* out = (float*)d_out;
    float* ws  = (float*)d_ws;

    const size_t F = (size_t)NSc * NXZ;
    float* xchg = ws;                              // 6 fields (2 parities)
    unsigned* flags = (unsigned*)(ws + 6 * F);     // 256 epoch counters

    // Flags must start at 0 every call (ws poisoned once, not re-poisoned).
    hipMemsetAsync(flags, 0, NBLK * sizeof(unsigned), stream);

    prop_kernel<<<NBLK, BT, 0, stream>>>(
        xchg, flags, vp, rho, damp, wavelet,
        src_x, src_z, rcv_x, rcv_z, out);
}

// Round 18
// 292.518 us; speedup vs baseline: 1.5636x; 1.0256x over previous
//
#include <hip/hip_runtime.h>

// Acoustic stress-velocity FD propagator, MI355X — persistent kernel v18.
// v15 (best, 286us) with the per-epoch staging DELETED via shadow
// persistence: central threads' vxm/vzm shadows are bit-correct across the
// epoch boundary (the shadow recursion only ever reads old-p values that
// are in-cone: row/col 15's p is consumed at its step-14 value), so no
// re-init is needed. Ring threads re-init shadows from the exchange buffer
// (2 extra dwordx4: vx(R-1), vz(z-1); clamped addresses where coefficient
// masks make the value irrelevant) and alone rewrite their sp_A slot.
// Saves 2 barriers + full-block staging per epoch. v17 lesson: no cone
// guard (barrier waits on central waves anyway; guard overhead nets
// negative). Sync protocol (all-far sc0 sc1, parity double-buffer, flag
// transitivity, proxy polls) bit-identical to v15.

#define NXc 256
#define NZc 256
#define NTc 400
#define NSc 4
#define NRc 128

#define TS 16                   // steps per epoch = halo depth
#define Bt 32                   // tile edge
#define LROW 64                 // region edge (z)
#define ROWS 64                 // region edge (x)
#define BT 1024                 // threads = 64 rows x 16 strips
#define SPSZ ((ROWS + 2) * LROW) // 4224 per p-buffer (pad row each side)
#define NBLK (NSc * 64)         // 256 blocks
#define NEP (NTc / TS)          // 25 epochs

constexpr float DT_H    = 0.001f;
constexpr float INV_D   = 0.1f;            // 1/DX = 1/DZ
constexpr float SRC_AMP = 0.001f * 0.01f;  // DT/(DX*DZ)
constexpr int   NXZ     = NXc * NZc;

typedef float f32x4 __attribute__((ext_vector_type(4)));

__device__ __forceinline__ unsigned ldu_far(const unsigned* p) {
    unsigned v;
    asm volatile("global_load_dword %0, %1, off sc0 sc1\n\t"
                 "s_waitcnt vmcnt(0)" : "=&v"(v) : "v"(p) : "memory");
    return v;
}
__device__ __forceinline__ void stu_far(unsigned* p, unsigned v) {
    asm volatile("global_store_dword %0, %1, off sc0 sc1"
                 :: "v"(p), "v"(v) : "memory");
}

__global__ __launch_bounds__(BT) void prop_kernel(
    float* __restrict__ xchg, unsigned* __restrict__ flags,
    const float* __restrict__ vp, const float* __restrict__ rho,
    const float* __restrict__ damp, const float* __restrict__ wavelet,
    const int* __restrict__ src_x, const int* __restrict__ src_z,
    const int* __restrict__ rcv_x, const int* __restrict__ rcv_z,
    float* __restrict__ out)
{
    __shared__ float sp[2 * SPSZ];   // double-buffered p (A=0, B=SPSZ)

    const int tid  = threadIdx.x;
    const int bid  = blockIdx.x;
    const int s    = bid >> 6;
    const int tile = bid & 63;
    const int tx = tile >> 3, tz = tile & 7;
    const int gx0 = tx * Bt - TS, gz0 = tz * Bt - TS;

    const int li  = tid >> 4;              // region row 0..63
    const int st  = tid & 15;              // strip 0..15
    const int lk0 = st * 4;
    const int gi  = gx0 + li;
    const int gk0 = gz0 + lk0;             // 4-aligned; strip fully in or out
    const bool in = ((unsigned)gi < (unsigned)NXc) &&
                    ((unsigned)gk0 < (unsigned)NZc);
    const int c4 = s * NXZ + gi * NZc + gk0;
    const bool central = in && ((unsigned)(li - TS) < (unsigned)Bt)
                            && (lk0 >= TS) && (lk0 <= TS + Bt - 4);
    const bool ring = in && !central;

    const size_t F = (size_t)NSc * NXZ;
    float* b0 = xchg;            // epoch parity 0: {p, vx, vz}
    float* b1 = xchg + 3 * F;    // epoch parity 1

    // ---- state + time-invariant coefficients (registers, once) ----
    float pr[4]  = {0, 0, 0, 0};
    float vxr[4] = {0, 0, 0, 0};
    float vzr[4] = {0, 0, 0, 0};
    float vxm[4] = {0, 0, 0, 0};   // shadow: vx of row R-1
    float vzm    = 0.f;            // shadow: vz of cell (gi, gk0-1)
    float fr[4], bxr[4], bzr[4], dkxr[4], dkzr[4], sfr[4];
    float fxm[4], bxm[4];          // row R-1 coefficients
    float fzm = 0.f, bzm = 0.f;    // cell (gi, gk0-1) coefficients
    {
        const int sx = src_x[s], sz = src_z[s];
        if (in) {
            const int g = gi * NZc + gk0;
            float4 r4 = *(const float4*)(rho  + g);
            float4 v4 = *(const float4*)(vp   + g);
            float4 d4 = *(const float4*)(damp + g);
            float rv[4] = {r4.x, r4.y, r4.z, r4.w};
            float vv[4] = {v4.x, v4.y, v4.z, v4.w};
            float dv[4] = {d4.x, d4.y, d4.z, d4.w};
#pragma unroll
            for (int k = 0; k < 4; ++k) {
                int gk = gk0 + k;
                fr[k] = 1.0f - DT_H * dv[k];
                float bi = DT_H / rv[k] * INV_D;
                bxr[k] = (gi == NXc - 1) ? 0.f : bi;   // _dxf zero-pad
                bzr[k] = (gk == NZc - 1) ? 0.f : bi;   // _dzf zero-pad
                float dk = DT_H * rv[k] * vv[k] * vv[k] * INV_D;
                dkxr[k] = (gi == 0) ? 0.f : dk;        // _dxb zero-pad
                dkzr[k] = (gk == 0) ? 0.f : dk;        // _dzb zero-pad
                sfr[k]  = (gi == sx && gk == sz) ? SRC_AMP : 0.f;
            }
            if (gi > 0) {
                float4 rm = *(const float4*)(rho  + g - NZc);
                float4 dm = *(const float4*)(damp + g - NZc);
                float rmv[4] = {rm.x, rm.y, rm.z, rm.w};
                float dmv[4] = {dm.x, dm.y, dm.z, dm.w};
#pragma unroll
                for (int k = 0; k < 4; ++k) {
                    fxm[k] = 1.0f - DT_H * dmv[k];
                    bxm[k] = DT_H / rmv[k] * INV_D;
                }
            } else {
#pragma unroll
                for (int k = 0; k < 4; ++k) { fxm[k] = 0.f; bxm[k] = 0.f; }
            }
            if (gk0 > 0) {
                fzm = 1.0f - DT_H * damp[g - 1];
                bzm = DT_H / rho[g - 1] * INV_D;
            }
        } else {
#pragma unroll
            for (int k = 0; k < 4; ++k) {
                fr[k]=0.f; bxr[k]=0.f; bzr[k]=0.f;
                dkxr[k]=0.f; dkzr[k]=0.f; sfr[k]=0.f;
                fxm[k]=0.f; bxm[k]=0.f;
            }
        }
    }

    const int jp = (li + 1) * LROW + lk0;

    // Zero pad rows of BOTH buffers + initial state (A holds p=0).
    if (tid < LROW) {
        sp[tid] = 0.f;               sp[SPSZ - LROW + tid] = 0.f;
        sp[SPSZ + tid] = 0.f;        sp[2 * SPSZ - LROW + tid] = 0.f;
    }
    *(f32x4*)&sp[jp] = f32x4{0, 0, 0, 0};

    // Receivers (loaded once).
    int rxv = 0, rzv = 0;
    if (tid < NRc) { rxv = rcv_x[tid]; rzv = rcv_z[tid]; }
    const bool rown = (tid < NRc) &&
        ((unsigned)(rxv - tx * Bt) < (unsigned)Bt) &&
        ((unsigned)(rzv - tz * Bt) < (unsigned)Bt);
    const int rj = (rxv - gx0 + 1) * LROW + (rzv - gz0);
    float* obase = out + (size_t)s * NTc * NRc + tid;
    const float* wb = wavelet + s * NTc;

    // Proxy-poll neighbor (tids 0..8, minus center 4).
    int nbid = -1;
    if (tid < 9 && tid != 4) {
        int dx = tid / 3 - 1, dz = tid - (tid / 3) * 3 - 1;
        int nx2 = tx + dx, nz2 = tz + dz;
        if (((unsigned)nx2 < 8u) && ((unsigned)nz2 < 8u))
            nbid = (s << 6) + nx2 * 8 + nz2;
    }

    // Shadow-source addresses (clamped when masked: fxm/bzm==0 there).
    const float* vxm_src = xchg;   // set per-epoch below (pb + offs)
    const int off_xm = (gi > 0)  ? (c4 - NZc) : c4;
    const int off_zm = (gk0 > 0) ? (c4 - 4)   : c4;

    // One fused step: read old p from rdo buffer, write new p to wro.
    auto STEP = [&](int rdo, int wro, int t, bool pub, float* pb) {
        f32x4 pn = *(const f32x4*)&sp[rdo + jp + LROW];   // old p(R+1)
        f32x4 pm = *(const f32x4*)&sp[rdo + jp - LROW];   // old p(R-1)
        float pze = __shfl_down(pr[0], 1, 64);  // next strip p[0] (old)
        float pmz = __shfl_up(pr[3], 1, 64);    // prev strip p[3] (old)
        float pz1[4] = {pr[1], pr[2], pr[3], pze};
#pragma unroll
        for (int k = 0; k < 4; ++k) {
            vxr[k] = fr[k] * vxr[k] - bxr[k] * (pn[k]  - pr[k]);
            vzr[k] = fr[k] * vzr[k] - bzr[k] * (pz1[k] - pr[k]);
        }
#pragma unroll
        for (int k = 0; k < 4; ++k)
            vxm[k] = fxm[k] * vxm[k] - bxm[k] * (pr[k] - pm[k]);
        vzm = fzm * vzm - bzm * (pr[0] - pmz);
        const float wv = wb[t];
        pr[0] = fr[0]*pr[0] - dkxr[0]*(vxr[0]-vxm[0])
              - dkzr[0]*(vzr[0]-vzm) + sfr[0]*wv;
#pragma unroll
        for (int k = 1; k < 4; ++k)
            pr[k] = fr[k]*pr[k] - dkxr[k]*(vxr[k]-vxm[k])
                  - dkzr[k]*(vzr[k]-vzr[k-1]) + sfr[k]*wv;
        if (pub) {
            f32x4 a = {pr[0], pr[1], pr[2], pr[3]};
            f32x4 b = {vxr[0], vxr[1], vxr[2], vxr[3]};
            f32x4 c = {vzr[0], vzr[1], vzr[2], vzr[3]};
            asm volatile(
                "global_store_dwordx4 %0, %3, off sc0 sc1\n\t"
                "global_store_dwordx4 %1, %4, off sc0 sc1\n\t"
                "global_store_dwordx4 %2, %5, off sc0 sc1"
                :: "v"(pb + c4), "v"(pb + F + c4), "v"(pb + 2 * F + c4),
                   "v"(a), "v"(b), "v"(c)
                : "memory");
        }
        *(f32x4*)&sp[wro + jp] = f32x4{pr[0], pr[1], pr[2], pr[3]};
        __syncthreads();
    };

    __syncthreads();   // initial sp_A writes visible

    for (int l = 0; l < NEP; ++l) {
        const bool notLast = (l < NEP - 1);
        float* pb = (l & 1) ? b1 : b0;

        // ---- TS fused steps; parity: even rd=A wr=B, odd rd=B wr=A ----
        const int tb = l * TS;
        for (int t2 = 0; t2 < TS; t2 += 2) {
            STEP(0, SPSZ, tb + t2, false, pb);
            if (rown)
                obase[(size_t)(tb + t2) * NRc] = sp[SPSZ + rj];
            const bool lastT = (t2 + 2 == TS);
            STEP(SPSZ, 0, tb + t2 + 1,
                 lastT && notLast && central, pb);
            if (!lastT && rown)
                obase[(size_t)(tb + t2 + 1) * NRc] = sp[rj];
        }

        if (notLast) {
            // Release: drain publish stores, then flag.
            asm volatile("s_waitcnt vmcnt(0)" ::: "memory");
            __syncthreads();
            if (tid == 0) stu_far(flags + bid, (unsigned)(l + 1));
            // last-tau receiver record overlaps the polls (final p in A).
            if (rown) obase[(size_t)(tb + TS - 1) * NRc] = sp[rj];
            // Proxy poll: 8 threads watch the 8 neighbors.
            if (nbid >= 0) {
                const unsigned want = (unsigned)(l + 1);
                const unsigned* fp = flags + nbid;
                while (ldu_far(fp) < want) __builtin_amdgcn_s_sleep(2);
            }
            __syncthreads();
            // Ring reload -> regs + shadow re-init + sp_A rewrite.
            // Central threads: state AND shadows are already correct
            // (shadow recursion stays in-cone through step 15).
            if (ring) {
                f32x4 a, b, c, xm, zm;
                asm volatile(
                    "global_load_dwordx4 %0, %5, off sc0 sc1\n\t"
                    "global_load_dwordx4 %1, %6, off sc0 sc1\n\t"
                    "global_load_dwordx4 %2, %7, off sc0 sc1\n\t"
                    "global_load_dwordx4 %3, %8, off sc0 sc1\n\t"
                    "global_load_dwordx4 %4, %9, off sc0 sc1\n\t"
                    "s_waitcnt vmcnt(0)"
                    : "=&v"(a), "=&v"(b), "=&v"(c), "=&v"(xm), "=&v"(zm)
                    : "v"(pb + c4), "v"(pb + F + c4), "v"(pb + 2 * F + c4),
                      "v"(pb + F + off_xm), "v"(pb + 2 * F + off_zm)
                    : "memory");
                pr[0]=a.x; pr[1]=a.y; pr[2]=a.z; pr[3]=a.w;
                vxr[0]=b.x; vxr[1]=b.y; vxr[2]=b.z; vxr[3]=b.w;
                vzr[0]=c.x; vzr[1]=c.y; vzr[2]=c.z; vzr[3]=c.w;
                vxm[0]=xm.x; vxm[1]=xm.y; vxm[2]=xm.z; vxm[3]=xm.w;
                vzm = zm.w;
                *(f32x4*)&sp[jp] = a;   // sp_A slot (step 0 reads A)
            }
            __syncthreads();   // ring sp_A writes visible before step 0
        } else {
            if (rown) obase[(size_t)(tb + TS - 1) * NRc] = sp[rj];
        }
    }
}

extern "C" void kernel_launch(void* const* d_in, const int* in_sizes, int n_in,
                              void* d_out, int out_size, void* d_ws, size_t ws_size,
                              hipStream_t stream)
{
    const float* vp      = (const float*)d_in[0];
    const float* rho     = (const float*)d_in[1];
    const float* damp    = (const float*)d_in[2];
    const float* wavelet = (const float*)d_in[3];
    const int*   src_x   = (const int*)d_in[4];
    const int*   src_z   = (const int*)d_in[5];
    const int*   rcv_x   = (const int*)d_in[6];
    const int*   rcv_z   = (const int*)d_in[7];
    float* out = (float*)d_out;
    float* ws  = (float*)d_ws;

    const size_t F = (size_t)NSc * NXZ;
    float* xchg = ws;                              // 6 fields (2 parities)
    unsigned* flags = (unsigned*)(ws + 6 * F);     // 256 epoch counters

    // Flags must start at 0 every call (ws poisoned once, not re-poisoned).
    hipMemsetAsync(flags, 0, NBLK * sizeof(unsigned), stream);

    prop_kernel<<<NBLK, BT, 0, stream>>>(
        xchg, flags, vp, rho, damp, wavelet,
        src_x, src_z, rcv_x, rcv_z, out);
}

// Round 20
// 286.053 us; speedup vs baseline: 1.5989x; 1.0226x over previous
//
#include <hip/hip_runtime.h>

// Acoustic stress-velocity FD propagator, MI355X — persistent kernel v20.
// = v15 VERBATIM (proven best: 286us) + one safe tweak: poll s_sleep(1).
// v19's lesson (now permanent): the explicit `s_waitcnt vmcnt(0)` +
// __syncthreads before the flag store is LOAD-BEARING — __syncthreads
// alone does NOT guarantee the compiler drains vmcnt for inline-asm
// global stores (it only must order intra-block visibility), so eliding
// it let the flag outrun the publish stores -> stale halos (absmax 8e-8).
// Structure: TS=16, 25 epochs, 256 blocks x 1024 thr (1 block/CU), fused
// one-barrier step with register shadows, double-buffered p in LDS,
// all-far (sc0 sc1 MALL) exchange, parity double-buffer + flag
// transitivity, 8 proxy pollers. Prior lessons: no near-scope sync
// (v8-v10 hangs), no co-residency (v7/v16), no cone guard (v17), keep
// epoch staging (v18), keep the release drain (v19).

#define NXc 256
#define NZc 256
#define NTc 400
#define NSc 4
#define NRc 128

#define TS 16                   // steps per epoch = halo depth
#define Bt 32                   // tile edge
#define LROW 64                 // region edge (z)
#define ROWS 64                 // region edge (x)
#define BT 1024                 // threads = 64 rows x 16 strips
#define SPSZ ((ROWS + 2) * LROW) // 4224 per p-buffer (pad row each side)
#define NBLK (NSc * 64)         // 256 blocks
#define NEP (NTc / TS)          // 25 epochs

constexpr float DT_H    = 0.001f;
constexpr float INV_D   = 0.1f;            // 1/DX = 1/DZ
constexpr float SRC_AMP = 0.001f * 0.01f;  // DT/(DX*DZ)
constexpr int   NXZ     = NXc * NZc;

typedef float f32x4 __attribute__((ext_vector_type(4)));

__device__ __forceinline__ unsigned ldu_far(const unsigned* p) {
    unsigned v;
    asm volatile("global_load_dword %0, %1, off sc0 sc1\n\t"
                 "s_waitcnt vmcnt(0)" : "=&v"(v) : "v"(p) : "memory");
    return v;
}
__device__ __forceinline__ void stu_far(unsigned* p, unsigned v) {
    asm volatile("global_store_dword %0, %1, off sc0 sc1"
                 :: "v"(p), "v"(v) : "memory");
}

__global__ __launch_bounds__(BT) void prop_kernel(
    float* __restrict__ xchg, unsigned* __restrict__ flags,
    const float* __restrict__ vp, const float* __restrict__ rho,
    const float* __restrict__ damp, const float* __restrict__ wavelet,
    const int* __restrict__ src_x, const int* __restrict__ src_z,
    const int* __restrict__ rcv_x, const int* __restrict__ rcv_z,
    float* __restrict__ out)
{
    __shared__ float sp[2 * SPSZ];   // double-buffered p (A=0, B=SPSZ)

    const int tid  = threadIdx.x;
    const int bid  = blockIdx.x;
    const int s    = bid >> 6;
    const int tile = bid & 63;
    const int tx = tile >> 3, tz = tile & 7;
    const int gx0 = tx * Bt - TS, gz0 = tz * Bt - TS;

    const int li  = tid >> 4;              // region row 0..63
    const int st  = tid & 15;              // strip 0..15
    const int lk0 = st * 4;
    const int gi  = gx0 + li;
    const int gk0 = gz0 + lk0;             // 4-aligned; strip fully in or out
    const bool in = ((unsigned)gi < (unsigned)NXc) &&
                    ((unsigned)gk0 < (unsigned)NZc);
    const int c4 = s * NXZ + gi * NZc + gk0;
    const bool central = in && ((unsigned)(li - TS) < (unsigned)Bt)
                            && (lk0 >= TS) && (lk0 <= TS + Bt - 4);
    const bool ring = in && !central;

    const size_t F = (size_t)NSc * NXZ;
    float* b0 = xchg;            // epoch parity 0: {p, vx, vz}
    float* b1 = xchg + 3 * F;    // epoch parity 1

    // ---- state + time-invariant coefficients (registers, once) ----
    float pr[4]  = {0, 0, 0, 0};
    float vxr[4] = {0, 0, 0, 0};
    float vzr[4] = {0, 0, 0, 0};
    float vxm[4] = {0, 0, 0, 0};   // shadow: vx of row R-1
    float vzm    = 0.f;            // shadow: vz of cell (gi, gk0-1)
    float fr[4], bxr[4], bzr[4], dkxr[4], dkzr[4], sfr[4];
    float fxm[4], bxm[4];          // row R-1 coefficients
    float fzm = 0.f, bzm = 0.f;    // cell (gi, gk0-1) coefficients
    {
        const int sx = src_x[s], sz = src_z[s];
        if (in) {
            const int g = gi * NZc + gk0;
            float4 r4 = *(const float4*)(rho  + g);
            float4 v4 = *(const float4*)(vp   + g);
            float4 d4 = *(const float4*)(damp + g);
            float rv[4] = {r4.x, r4.y, r4.z, r4.w};
            float vv[4] = {v4.x, v4.y, v4.z, v4.w};
            float dv[4] = {d4.x, d4.y, d4.z, d4.w};
#pragma unroll
            for (int k = 0; k < 4; ++k) {
                int gk = gk0 + k;
                fr[k] = 1.0f - DT_H * dv[k];
                float bi = DT_H / rv[k] * INV_D;
                bxr[k] = (gi == NXc - 1) ? 0.f : bi;   // _dxf zero-pad
                bzr[k] = (gk == NZc - 1) ? 0.f : bi;   // _dzf zero-pad
                float dk = DT_H * rv[k] * vv[k] * vv[k] * INV_D;
                dkxr[k] = (gi == 0) ? 0.f : dk;        // _dxb zero-pad
                dkzr[k] = (gk == 0) ? 0.f : dk;        // _dzb zero-pad
                sfr[k]  = (gi == sx && gk == sz) ? SRC_AMP : 0.f;
            }
            if (gi > 0) {
                float4 rm = *(const float4*)(rho  + g - NZc);
                float4 dm = *(const float4*)(damp + g - NZc);
                float rmv[4] = {rm.x, rm.y, rm.z, rm.w};
                float dmv[4] = {dm.x, dm.y, dm.z, dm.w};
#pragma unroll
                for (int k = 0; k < 4; ++k) {
                    fxm[k] = 1.0f - DT_H * dmv[k];
                    bxm[k] = DT_H / rmv[k] * INV_D;
                }
            } else {
#pragma unroll
                for (int k = 0; k < 4; ++k) { fxm[k] = 0.f; bxm[k] = 0.f; }
            }
            if (gk0 > 0) {
                fzm = 1.0f - DT_H * damp[g - 1];
                bzm = DT_H / rho[g - 1] * INV_D;
            }
        } else {
#pragma unroll
            for (int k = 0; k < 4; ++k) {
                fr[k]=0.f; bxr[k]=0.f; bzr[k]=0.f;
                dkxr[k]=0.f; dkzr[k]=0.f; sfr[k]=0.f;
                fxm[k]=0.f; bxm[k]=0.f;
            }
        }
    }

    const int jp = (li + 1) * LROW + lk0;

    // Zero pad rows of BOTH buffers (steps write rows 0..63 only).
    if (tid < LROW) {
        sp[tid] = 0.f;               sp[SPSZ - LROW + tid] = 0.f;
        sp[SPSZ + tid] = 0.f;        sp[2 * SPSZ - LROW + tid] = 0.f;
    }

    // Receivers (loaded once).
    int rxv = 0, rzv = 0;
    if (tid < NRc) { rxv = rcv_x[tid]; rzv = rcv_z[tid]; }
    const bool rown = (tid < NRc) &&
        ((unsigned)(rxv - tx * Bt) < (unsigned)Bt) &&
        ((unsigned)(rzv - tz * Bt) < (unsigned)Bt);
    const int rj = (rxv - gx0 + 1) * LROW + (rzv - gz0);
    float* obase = out + (size_t)s * NTc * NRc + tid;
    const float* wb = wavelet + s * NTc;

    // Proxy-poll neighbor (tids 0..8, minus center 4).
    int nbid = -1;
    if (tid < 9 && tid != 4) {
        int dx = tid / 3 - 1, dz = tid - (tid / 3) * 3 - 1;
        int nx2 = tx + dx, nz2 = tz + dz;
        if (((unsigned)nx2 < 8u) && ((unsigned)nz2 < 8u))
            nbid = (s << 6) + nx2 * 8 + nz2;
    }

    // One fused step: read old p from rdo buffer, write new p to wro.
    auto STEP = [&](int rdo, int wro, int t, bool pub, float* pb) {
        f32x4 pn = *(const f32x4*)&sp[rdo + jp + LROW];   // old p(R+1)
        f32x4 pm = *(const f32x4*)&sp[rdo + jp - LROW];   // old p(R-1)
        float pze = __shfl_down(pr[0], 1, 64);  // next strip p[0] (old)
        float pmz = __shfl_up(pr[3], 1, 64);    // prev strip p[3] (old)
        float pz1[4] = {pr[1], pr[2], pr[3], pze};
#pragma unroll
        for (int k = 0; k < 4; ++k) {
            vxr[k] = fr[k] * vxr[k] - bxr[k] * (pn[k]  - pr[k]);
            vzr[k] = fr[k] * vzr[k] - bzr[k] * (pz1[k] - pr[k]);
        }
#pragma unroll
        for (int k = 0; k < 4; ++k)
            vxm[k] = fxm[k] * vxm[k] - bxm[k] * (pr[k] - pm[k]);
        vzm = fzm * vzm - bzm * (pr[0] - pmz);
        const float wv = wb[t];
        pr[0] = fr[0]*pr[0] - dkxr[0]*(vxr[0]-vxm[0])
              - dkzr[0]*(vzr[0]-vzm) + sfr[0]*wv;
#pragma unroll
        for (int k = 1; k < 4; ++k)
            pr[k] = fr[k]*pr[k] - dkxr[k]*(vxr[k]-vxm[k])
                  - dkzr[k]*(vzr[k]-vzr[k-1]) + sfr[k]*wv;
        if (pub) {
            f32x4 a = {pr[0], pr[1], pr[2], pr[3]};
            f32x4 b = {vxr[0], vxr[1], vxr[2], vxr[3]};
            f32x4 c = {vzr[0], vzr[1], vzr[2], vzr[3]};
            asm volatile(
                "global_store_dwordx4 %0, %3, off sc0 sc1\n\t"
                "global_store_dwordx4 %1, %4, off sc0 sc1\n\t"
                "global_store_dwordx4 %2, %5, off sc0 sc1"
                :: "v"(pb + c4), "v"(pb + F + c4), "v"(pb + 2 * F + c4),
                   "v"(a), "v"(b), "v"(c)
                : "memory");
        }
        *(f32x4*)&sp[wro + jp] = f32x4{pr[0], pr[1], pr[2], pr[3]};
        __syncthreads();
    };

    for (int l = 0; l < NEP; ++l) {
        const bool notLast = (l < NEP - 1);
        float* pb = (l & 1) ? b1 : b0;

        // ---- epoch setup: p -> A; stage vx in B for shadow init ----
        *(f32x4*)&sp[jp]        = f32x4{pr[0], pr[1], pr[2], pr[3]};
        *(f32x4*)&sp[SPSZ + jp] = f32x4{vxr[0], vxr[1], vxr[2], vxr[3]};
        __syncthreads();
        {
            f32x4 vm = *(const f32x4*)&sp[SPSZ + jp - LROW];
            vxm[0]=vm[0]; vxm[1]=vm[1]; vxm[2]=vm[2]; vxm[3]=vm[3];
            vzm = __shfl_up(vzr[3], 1, 64);
        }
        __syncthreads();   // shadow reads done before step 0 writes to B

        // ---- TS fused steps; parity: even rd=A wr=B, odd rd=B wr=A ----
        const int tb = l * TS;
        for (int t2 = 0; t2 < TS; t2 += 2) {
            STEP(0, SPSZ, tb + t2, false, pb);
            if (rown)
                obase[(size_t)(tb + t2) * NRc] = sp[SPSZ + rj];
            const bool lastT = (t2 + 2 == TS);
            STEP(SPSZ, 0, tb + t2 + 1,
                 lastT && notLast && central, pb);
            if (!lastT && rown)
                obase[(size_t)(tb + t2 + 1) * NRc] = sp[rj];
        }

        if (notLast) {
            // Release: drain publish stores (LOAD-BEARING — see header),
            // then block-wide barrier, then flag.
            asm volatile("s_waitcnt vmcnt(0)" ::: "memory");
            __syncthreads();
            if (tid == 0) stu_far(flags + bid, (unsigned)(l + 1));
            // last-tau receiver record overlaps the polls (final p in A).
            if (rown) obase[(size_t)(tb + TS - 1) * NRc] = sp[rj];
            // Proxy poll: 8 threads watch the 8 neighbors.
            if (nbid >= 0) {
                const unsigned want = (unsigned)(l + 1);
                const unsigned* fp = flags + nbid;
                while (ldu_far(fp) < want) __builtin_amdgcn_s_sleep(1);
            }
            __syncthreads();
            // Ring reload -> regs (epoch setup re-stages LDS + shadows).
            if (ring) {
                f32x4 a, b, c;
                asm volatile(
                    "global_load_dwordx4 %0, %3, off sc0 sc1\n\t"
                    "global_load_dwordx4 %1, %4, off sc0 sc1\n\t"
                    "global_load_dwordx4 %2, %5, off sc0 sc1\n\t"
                    "s_waitcnt vmcnt(0)"
                    : "=&v"(a), "=&v"(b), "=&v"(c)
                    : "v"(pb + c4), "v"(pb + F + c4), "v"(pb + 2 * F + c4)
                    : "memory");
                pr[0]=a.x; pr[1]=a.y; pr[2]=a.z; pr[3]=a.w;
                vxr[0]=b.x; vxr[1]=b.y; vxr[2]=b.z; vxr[3]=b.w;
                vzr[0]=c.x; vzr[1]=c.y; vzr[2]=c.z; vzr[3]=c.w;
            }
        } else {
            if (rown) obase[(size_t)(tb + TS - 1) * NRc] = sp[rj];
        }
    }
}

extern "C" void kernel_launch(void* const* d_in, const int* in_sizes, int n_in,
                              void* d_out, int out_size, void* d_ws, size_t ws_size,
                              hipStream_t stream)
{
    const float* vp      = (const float*)d_in[0];
    const float* rho     = (const float*)d_in[1];
    const float* damp    = (const float*)d_in[2];
    const float* wavelet = (const float*)d_in[3];
    const int*   src_x   = (const int*)d_in[4];
    const int*   src_z   = (const int*)d_in[5];
    const int*   rcv_x   = (const int*)d_in[6];
    const int*   rcv_z   = (const int*)d_in[7];
    float* out = (float*)d_out;
    float* ws  = (float*)d_ws;

    const size_t F = (size_t)NSc * NXZ;
    float* xchg = ws;                              // 6 fields (2 parities)
    unsigned* flags = (unsigned*)(ws + 6 * F);     // 256 epoch counters

    // Flags must start at 0 every call (ws poisoned once, not re-poisoned).
    hipMemsetAsync(flags, 0, NBLK * sizeof(unsigned), stream);

    prop_kernel<<<NBLK, BT, 0, stream>>>(
        xchg, flags, vp, rho, damp, wavelet,
        src_x, src_z, rcv_x, rcv_z, out);
}